// Round 6
// baseline (467.308 us; speedup 1.0000x reference)
//
#include <hip/hip_runtime.h>

#define N_NODES  100000
#define N_EDGES  1600000
#define NF       128
#define N_GRAPHS 100
#define NBKT     391         // ceil(100000 / 256) coarse buckets
#define BKT_SHIFT 8
#define CAP      6144        // coarse bucket capacity; mean 4092, +32 sigma (fixed input)
#define CAPN     48          // per-node CSR capacity; Poisson(16), P(deg>48) ~ 7e-11/node
#define EPB      4096        // edges per block in bscatter (R1-proven config)
#define EB_GRID  391
#define FBLOCKS  782         // fused gather+mlp blocks (128 rows each)

typedef __attribute__((ext_vector_type(8))) short bf16x8;
typedef __attribute__((ext_vector_type(4))) float f32x4;
typedef __attribute__((ext_vector_type(2))) float f32x2;
typedef unsigned int uint32;

// ---------------------------------------------------------------- bf16 helpers (RNE)
__device__ __forceinline__ unsigned short f2bf(float f) {
    union { float f; uint32 u; } x; x.f = f;
    return (unsigned short)((x.u + 0x7fffu + ((x.u >> 16) & 1u)) >> 16);
}
__device__ __forceinline__ uint32 pack2bf(float a, float b) {
    union { float f; uint32 u; } x, y; x.f = a; y.f = b;
    uint32 lo = (x.u + 0x7fffu + ((x.u >> 16) & 1u)) >> 16;
    uint32 hi = (y.u + 0x7fffu + ((y.u >> 16) & 1u)) & 0xffff0000u;
    return lo | hi;
}
__device__ __forceinline__ void add8(f32x2* acc, uint4 u4) {
    uint32 u[4] = {u4.x, u4.y, u4.z, u4.w};
    #pragma unroll
    for (int i = 0; i < 4; ++i) {
        union { uint32 b; float f; } lo, hi;
        lo.b = u[i] << 16; hi.b = u[i] & 0xffff0000u;
        acc[i] += (f32x2){lo.f, hi.f};
    }
}

// ---------------------------------------------------------------- prep (R1-proven): x->bf16, W1..4->bf16, zero cursors+sums
__global__ __launch_bounds__(256) void prep(const float4* __restrict__ x,
                                            const float4* __restrict__ w1,
                                            const float4* __restrict__ w2,
                                            const float4* __restrict__ w3,
                                            const float4* __restrict__ w4,
                                            uint4* __restrict__ xb, uint4* __restrict__ wb,
                                            int* __restrict__ cur, float* __restrict__ sums) {
    int bid = blockIdx.x, t = threadIdx.x;
    if (bid < 6250) {                               // x: 1.6M uint4 outputs exactly
        int i = bid * 256 + t;
        float4 a = x[i * 2], b = x[i * 2 + 1];
        uint4 o;
        o.x = pack2bf(a.x, a.y); o.y = pack2bf(a.z, a.w);
        o.z = pack2bf(b.x, b.y); o.w = pack2bf(b.z, b.w);
        xb[i] = o;
    } else if (bid < 6282) {                        // weights: 8192 uint4
        int i = (bid - 6250) * 256 + t;
        int wi = i >> 11, li = i & 2047;
        const float4* s = (wi == 0) ? w1 : (wi == 1) ? w2 : (wi == 2) ? w3 : w4;
        float4 a = s[li * 2], b = s[li * 2 + 1];
        uint4 o;
        o.x = pack2bf(a.x, a.y); o.y = pack2bf(a.z, a.w);
        o.z = pack2bf(b.x, b.y); o.w = pack2bf(b.z, b.w);
        wb[i] = o;
    } else {                                        // zero cur[391] + sums[12800]
        int idx = (bid - 6282) * 256 + t;           // 16 blocks -> 4096 threads
        for (int i = idx; i < N_GRAPHS * NF; i += 4096) sums[i] = 0.f;
        if (idx < NBKT) cur[idx] = 0;
    }
}

// ---------------------------------------------------------------- CSR A (R1-proven): scatter edges into coarse buckets
// packed entry: (dstLocal<<17) | src   (src < 131072, dstLocal < 256)
__global__ __launch_bounds__(512) void bscatter(const int* __restrict__ src,
                                                const int* __restrict__ dst,
                                                int* __restrict__ cur,
                                                uint32* __restrict__ ebuf) {
    __shared__ int lh[NBKT], lbase[NBKT];
    int t = threadIdx.x;
    if (t < NBKT) lh[t] = 0;
    __syncthreads();
    int e0 = blockIdx.x * EPB;
    int d[8];
    #pragma unroll
    for (int i = 0; i < 8; ++i) {
        int e = e0 + i * 512 + t;
        d[i] = -1;
        if (e < N_EDGES) { d[i] = dst[e]; atomicAdd(&lh[d[i] >> BKT_SHIFT], 1); }
    }
    __syncthreads();
    if (t < NBKT) { lbase[t] = t * CAP + (lh[t] ? atomicAdd(&cur[t], lh[t]) : 0); lh[t] = 0; }
    __syncthreads();
    #pragma unroll
    for (int i = 0; i < 8; ++i) {
        int e = e0 + i * 512 + t;
        if (e < N_EDGES) {
            int b = d[i] >> BKT_SHIFT;
            int off = atomicAdd(&lh[b], 1);
            ebuf[lbase[b] + off] = ((uint32)(d[i] & 255) << 17) | (uint32)src[e];
        }
    }
}

// ---------------------------------------------------------------- CSR B (R3-proven): bucket -> fixed-cap per-node rows via LDS
// Rows built in LDS (49KB) then written out as coalesced uint4 (48KB contiguous
// per bucket). Unfilled slots carry garbage - gather only consumes slots < deg.
__global__ __launch_bounds__(256) void bfine(const uint32* __restrict__ ebuf,
                                             const int* __restrict__ cur,
                                             int* __restrict__ cnt,
                                             int* __restrict__ csr) {
    __shared__ int off[256];
    __shared__ __align__(16) int lcsr[256 * CAPN];  // 49KB
    int t = threadIdx.x;
    int bkt = blockIdx.x;
    int beg = bkt * CAP;
    int end = beg + min(cur[bkt], CAP);
    off[t] = 0;
    __syncthreads();
    for (int e = beg + t; e < end; e += 256) {
        uint32 u = ebuf[e];
        int local = (int)(u >> 17);
        int pos = atomicAdd(&off[local], 1);
        if (pos < CAPN)
            lcsr[local * CAPN + pos] = (int)(u & 0x1FFFFu);
    }
    __syncthreads();
    int node = (bkt << BKT_SHIFT) + t;
    if (node < N_NODES) cnt[node] = min(off[t], CAPN);
    uint4* dstq = (uint4*)(csr + (size_t)bkt * 256 * CAPN);
    const uint4* srcq = (const uint4*)lcsr;
    for (int i = t; i < 256 * CAPN / 4; i += 256)   // 3072 uint4, fully coalesced
        dstq[i] = srcq[i];
}

// ---------------------------------------------------------------- R6: fused gather + 2-layer MLP per block
// 512 threads = 8 waves; block owns 128 output rows. Each wave gathers its OWN
// 16 rows into LDS (v3 wave-gather body, bf16 RNE pack - numerically identical
// to the old t0 path), then MFMAs those same rows. Node-set == row-set per wave,
// so there are no cross-wave data dependencies; barriers only guard the LDS
// buffer reuse (A -> Mid). Kills the t0 global round-trip and the standalone
// MLP's global-A latency; MFMA phase appends ~8-10us to the gather phase.
// LDS 34.8KB -> 4 blocks/CU; VGPR ~64 -> up to 32 waves/CU during gather.
template <bool F32OUT>
__global__ __launch_bounds__(512) void fused_gml(const uint4* __restrict__ x,
                                                 const int* __restrict__ cnt,
                                                 const int* __restrict__ csr,
                                                 const unsigned short* __restrict__ Wa,
                                                 const float* __restrict__ ba,
                                                 const unsigned short* __restrict__ Wb,
                                                 const float* __restrict__ bb,
                                                 void* __restrict__ Cout) {
    __shared__ __align__(16) unsigned short AM[128 * 136];  // A, then Mid (reused)
    int tid = threadIdx.x;
    int wv = tid >> 6;           // 0..7
    int l  = tid & 63;
    int c = l & 15;              // feature chunk (16B) in gather / col lane in mfma
    int j = l >> 4;              // edge slot 0..3 in gather / q in mfma
    int row0 = blockIdx.x * 128;

    // ---- phase 1: gather 16 consecutive nodes per wave into AM[wv*16 .. wv*16+16)
    for (int i = 0; i < 16; ++i) {
        int lrow = wv * 16 + i;
        int node = min(row0 + lrow, N_NODES - 1);
        int beg = node * CAPN;

        uint4 vself = x[(size_t)node * 16 + c];
        int myE = csr[beg + min(l, CAPN - 1)];
        int deg = cnt[node];

        f32x2 acc[4];
        #pragma unroll
        for (int a = 0; a < 4; ++a) acc[a] = (f32x2){0.f, 0.f};

        uint4 v[8];
        int ok[8];
        #pragma unroll
        for (int k = 0; k < 4; ++k) {                // tile 0: slots 0..15
            int sl = j + 4 * k;
            int sle = max(min(sl, deg - 1), 0);
            unsigned s = (unsigned)__shfl(myE, sle, 64);
            s = min(s, (unsigned)(N_NODES - 1));
            v[k] = x[(size_t)s * 16 + c];
            ok[k] = sl < deg;
        }
        if (deg > 16) {                              // tile 1: slots 16..31 (uniform branch)
            #pragma unroll
            for (int k = 0; k < 4; ++k) {
                int sl = 16 + j + 4 * k;
                int sle = min(sl, deg - 1);
                unsigned s = (unsigned)__shfl(myE, sle, 64);
                s = min(s, (unsigned)(N_NODES - 1));
                v[4 + k] = x[(size_t)s * 16 + c];
                ok[4 + k] = sl < deg;
            }
        }
        #pragma unroll
        for (int k = 0; k < 4; ++k) if (ok[k]) add8(acc, v[k]);
        if (deg > 16) {
            #pragma unroll
            for (int k = 0; k < 4; ++k) if (ok[4 + k]) add8(acc, v[4 + k]);
            for (int sl0 = 32; sl0 < deg; sl0 += 16) {   // rare tail
                #pragma unroll
                for (int k = 0; k < 4; ++k) {
                    int sl = sl0 + j + 4 * k;
                    int sle = min(sl, deg - 1);
                    unsigned s = (unsigned)__shfl(myE, sle, 64);
                    s = min(s, (unsigned)(N_NODES - 1));
                    uint4 vv = x[(size_t)s * 16 + c];
                    if (sl < deg) add8(acc, vv);
                }
            }
        }

        // reduce 4 edge-slot partials: lanes l, l^16, l^32, l^48 share chunk c
        #pragma unroll
        for (int a = 0; a < 4; ++a) {
            acc[a].x += __shfl_xor(acc[a].x, 16, 64);
            acc[a].y += __shfl_xor(acc[a].y, 16, 64);
            acc[a].x += __shfl_xor(acc[a].x, 32, 64);
            acc[a].y += __shfl_xor(acc[a].y, 32, 64);
        }

        add8(acc, vself);                            // self term

        if (j == 0) {                                // 16 lanes write the bf16 row to LDS
            uint4 o;
            o.x = pack2bf(acc[0].x, acc[0].y); o.y = pack2bf(acc[1].x, acc[1].y);
            o.z = pack2bf(acc[2].x, acc[2].y); o.w = pack2bf(acc[3].x, acc[3].y);
            *(uint4*)&AM[lrow * 136 + c * 8] = o;    // 272B row stride, 16B aligned
        }
    }
    __syncthreads();

    // ---- phase 2: pass 1  mid = relu(A @ Wa^T + ba)   (wave owns rows wv*16..+16)
    int lm = c, q = j;
    const unsigned short* pa  = &AM[(wv * 16 + lm) * 136];
    const unsigned short* pwa = Wa + lm * NF;
    const unsigned short* pwb = Wb + lm * NF;

    f32x4 acc[8];
    #pragma unroll
    for (int ct = 0; ct < 8; ++ct) acc[ct] = (f32x4){0.f, 0.f, 0.f, 0.f};

    #pragma unroll
    for (int ks = 0; ks < 4; ++ks) {
        int ko = ks * 32 + q * 8;
        bf16x8 a = *(const bf16x8*)(pa + ko);
        #pragma unroll
        for (int ct = 0; ct < 8; ++ct) {
            bf16x8 b = *(const bf16x8*)(pwa + ct * 16 * NF + ko);
            acc[ct] = __builtin_amdgcn_mfma_f32_16x16x32_bf16(a, b, acc[ct], 0, 0, 0);
        }
    }
    __syncthreads();                                 // all A-reads done before Mid overwrite

    #pragma unroll
    for (int ct = 0; ct < 8; ++ct) {
        int col = ct * 16 + lm;
        float bv = ba[col];
        #pragma unroll
        for (int r = 0; r < 4; ++r) {
            int rr = wv * 16 + q * 4 + r;
            AM[rr * 136 + col] = f2bf(fmaxf(acc[ct][r] + bv, 0.f));
        }
    }
    __syncthreads();                                 // Mid complete before pass-2 reads

    // ---- pass 2: out = relu(mid @ Wb^T + bb)
    #pragma unroll
    for (int ct = 0; ct < 8; ++ct) acc[ct] = (f32x4){0.f, 0.f, 0.f, 0.f};

    #pragma unroll
    for (int ks = 0; ks < 4; ++ks) {
        int ko = ks * 32 + q * 8;
        bf16x8 a = *(const bf16x8*)(pa + ko);        // same rows, now holding Mid
        #pragma unroll
        for (int ct = 0; ct < 8; ++ct) {
            bf16x8 b = *(const bf16x8*)(pwb + ct * 16 * NF + ko);
            acc[ct] = __builtin_amdgcn_mfma_f32_16x16x32_bf16(a, b, acc[ct], 0, 0, 0);
        }
    }

    #pragma unroll
    for (int ct = 0; ct < 8; ++ct) {
        int col = ct * 16 + lm;
        float bv = bb[col];
        #pragma unroll
        for (int r = 0; r < 4; ++r) {
            int row = row0 + wv * 16 + q * 4 + r;
            if (row < N_NODES) {
                float vv = fmaxf(acc[ct][r] + bv, 0.f);
                if (F32OUT) ((float*)Cout)[(size_t)row * NF + col] = vv;
                else ((unsigned short*)Cout)[(size_t)row * NF + col] = f2bf(vv);
            }
        }
    }
}

// ---------------------------------------------------------------- pooling (batch sorted), float4 loads, 782 blocks
__global__ __launch_bounds__(256) void pool_sum4(const float4* __restrict__ h,
                                                 const int* __restrict__ batch,
                                                 float* __restrict__ sums) {
    int t = threadIdx.x;
    int f4 = t & 31, seg = t >> 5;                   // 8 segs x 32 float4-lanes
    int n0 = blockIdx.x * 128 + seg * 16;
    if (n0 >= N_NODES) return;
    int n1 = min(n0 + 16, N_NODES);
    int cur = batch[n0];
    float4 acc = {0.f, 0.f, 0.f, 0.f};
    for (int n = n0; n < n1; ++n) {
        int g = batch[n];
        if (g != cur) {
            atomicAdd(&sums[cur * NF + f4 * 4 + 0], acc.x);
            atomicAdd(&sums[cur * NF + f4 * 4 + 1], acc.y);
            atomicAdd(&sums[cur * NF + f4 * 4 + 2], acc.z);
            atomicAdd(&sums[cur * NF + f4 * 4 + 3], acc.w);
            acc = (float4){0.f, 0.f, 0.f, 0.f}; cur = g;
        }
        float4 v = h[(size_t)n * 32 + f4];
        acc.x += v.x; acc.y += v.y; acc.z += v.z; acc.w += v.w;
    }
    atomicAdd(&sums[cur * NF + f4 * 4 + 0], acc.x);
    atomicAdd(&sums[cur * NF + f4 * 4 + 1], acc.y);
    atomicAdd(&sums[cur * NF + f4 * 4 + 2], acc.z);
    atomicAdd(&sums[cur * NF + f4 * 4 + 3], acc.w);
}

__global__ __launch_bounds__(256) void pool_div2(const float* __restrict__ sums,
                                                 const int* __restrict__ batch,
                                                 float* __restrict__ out) {
    int i = blockIdx.x * 256 + threadIdx.x;
    if (i >= N_GRAPHS * NF) return;
    int g = i >> 7;
    int lo = 0, hi = N_NODES;
    while (lo < hi) { int m = (lo + hi) >> 1; if (batch[m] < g) lo = m + 1; else hi = m; }
    int lo2 = lo, hi2 = N_NODES;
    while (lo2 < hi2) { int m = (lo2 + hi2) >> 1; if (batch[m] < g + 1) lo2 = m + 1; else hi2 = m; }
    float cnt = (float)(lo2 - lo);
    out[i] = sums[i] / fmaxf(cnt, 1.f);
}

// ----------------------------------------------------------------
extern "C" void kernel_launch(void* const* d_in, const int* in_sizes, int n_in,
                              void* d_out, int out_size, void* d_ws, size_t ws_size,
                              hipStream_t stream) {
    const float* x     = (const float*)d_in[0];
    const int*   ei    = (const int*)d_in[1];
    const int*   batch = (const int*)d_in[2];
    const float* W1 = (const float*)d_in[3];  const float* b1 = (const float*)d_in[4];
    const float* W2 = (const float*)d_in[5];  const float* b2 = (const float*)d_in[6];
    const float* W3 = (const float*)d_in[7];  const float* b3 = (const float*)d_in[8];
    const float* W4 = (const float*)d_in[9];  const float* b4 = (const float*)d_in[10];
    const int* src = ei;
    const int* dst = ei + N_EDGES;

    float* out   = (float*)d_out;
    float* h_out = out + N_GRAPHS * NF;            // 100000x128 fp32 (2nd output)

    // workspace (~71 MB; ebuf aliases t1 — t1 only written by F1 after bfine)
    const size_t NE = (size_t)N_NODES * NF;        // 12.8M
    unsigned short* xb = (unsigned short*)d_ws;    // bf16 x            25.6 MB
    unsigned short* t1 = xb + NE;                  // bf16 h1           25.6 MB
    unsigned short* Wb = t1 + NE;                  // 4 x 128x128 bf16  0.13 MB
    int*    csr  = (int*)(Wb + 4 * NF * NF);       // NBKT*256*CAPN     19.2 MB (bucket-padded)
    int*    cntp = csr + (size_t)NBKT * 256 * CAPN;// N_NODES           0.4 MB
    int*    curp = cntp + N_NODES;                 // NBKT
    float*  sums = (float*)(curp + NBKT);          // N_GRAPHS*NF
    uint32* ebuf = (uint32*)t1;                    // alias: 9.6 MB <= 25.6 MB

    // ---- prep: bf16 conversions + zero cursors/sums (one launch, no memsets)
    prep<<<6250 + 32 + 16, 256, 0, stream>>>((const float4*)x,
                                             (const float4*)W1, (const float4*)W2,
                                             (const float4*)W3, (const float4*)W4,
                                             (uint4*)xb, (uint4*)Wb, curp, sums);

    // ---- CSR build (coarse bucket scatter, then LDS-staged fixed-cap rows)
    bscatter<<<EB_GRID, 512, 0, stream>>>(src, dst, curp, ebuf);
    bfine<<<NBKT, 256, 0, stream>>>(ebuf, curp, cntp, csr);

    // ---- layer 1: fused gather+MLP1 -> t1 (bf16)
    fused_gml<false><<<FBLOCKS, 512, 0, stream>>>((const uint4*)xb, cntp, csr,
                                                  Wb + 0 * NF * NF, b1,
                                                  Wb + 1 * NF * NF, b2, t1);

    // ---- layer 2: fused gather+MLP2 -> h_out (f32)
    fused_gml<true ><<<FBLOCKS, 512, 0, stream>>>((const uint4*)t1, cntp, csr,
                                                  Wb + 2 * NF * NF, b3,
                                                  Wb + 3 * NF * NF, b4, h_out);

    // ---- global mean pool
    pool_sum4<<<(N_NODES + 127) / 128, 256, 0, stream>>>((const float4*)h_out, batch, sums);
    pool_div2<<<(N_GRAPHS * NF + 255) / 256, 256, 0, stream>>>(sums, batch, out);
}

// Round 7
// 439.381 us; speedup vs baseline: 1.0636x; 1.0636x over previous
//
#include <hip/hip_runtime.h>

#define N_NODES  100000
#define N_EDGES  1600000
#define NF       128
#define N_GRAPHS 100
#define NBKT     391         // ceil(100000 / 256) coarse buckets
#define BKT_SHIFT 8
#define CAP      6144        // coarse bucket capacity; mean 4092, +32 sigma (fixed input)
#define CAPN     48          // per-node CSR capacity; Poisson(16), P(deg>48) ~ 7e-11/node
#define EPB      2048        // edges per block in bscatter (782 blocks = 3.05/CU)
#define EB_GRID  782
#define MBLK64   1563        // ceil(100000/64) mlp blocks

typedef __attribute__((ext_vector_type(8))) short bf16x8;
typedef __attribute__((ext_vector_type(4))) float f32x4;
typedef __attribute__((ext_vector_type(2))) float f32x2;
typedef unsigned int uint32;

// ---------------------------------------------------------------- bf16 helpers (RNE)
__device__ __forceinline__ unsigned short f2bf(float f) {
    union { float f; uint32 u; } x; x.f = f;
    return (unsigned short)((x.u + 0x7fffu + ((x.u >> 16) & 1u)) >> 16);
}
__device__ __forceinline__ uint32 pack2bf(float a, float b) {
    union { float f; uint32 u; } x, y; x.f = a; y.f = b;
    uint32 lo = (x.u + 0x7fffu + ((x.u >> 16) & 1u)) >> 16;
    uint32 hi = (y.u + 0x7fffu + ((y.u >> 16) & 1u)) & 0xffff0000u;
    return lo | hi;
}
__device__ __forceinline__ void add8(f32x2* acc, uint4 u4) {
    uint32 u[4] = {u4.x, u4.y, u4.z, u4.w};
    #pragma unroll
    for (int i = 0; i < 4; ++i) {
        union { uint32 b; float f; } lo, hi;
        lo.b = u[i] << 16; hi.b = u[i] & 0xffff0000u;
        acc[i] += (f32x2){lo.f, hi.f};
    }
}

// ---------------------------------------------------------------- prep (R1-proven): x->bf16, W1..4->bf16, zero cursors+sums
__global__ __launch_bounds__(256) void prep(const float4* __restrict__ x,
                                            const float4* __restrict__ w1,
                                            const float4* __restrict__ w2,
                                            const float4* __restrict__ w3,
                                            const float4* __restrict__ w4,
                                            uint4* __restrict__ xb, uint4* __restrict__ wb,
                                            int* __restrict__ cur, float* __restrict__ sums) {
    int bid = blockIdx.x, t = threadIdx.x;
    if (bid < 6250) {                               // x: 1.6M uint4 outputs exactly
        int i = bid * 256 + t;
        float4 a = x[i * 2], b = x[i * 2 + 1];
        uint4 o;
        o.x = pack2bf(a.x, a.y); o.y = pack2bf(a.z, a.w);
        o.z = pack2bf(b.x, b.y); o.w = pack2bf(b.z, b.w);
        xb[i] = o;
    } else if (bid < 6282) {                        // weights: 8192 uint4
        int i = (bid - 6250) * 256 + t;
        int wi = i >> 11, li = i & 2047;
        const float4* s = (wi == 0) ? w1 : (wi == 1) ? w2 : (wi == 2) ? w3 : w4;
        float4 a = s[li * 2], b = s[li * 2 + 1];
        uint4 o;
        o.x = pack2bf(a.x, a.y); o.y = pack2bf(a.z, a.w);
        o.z = pack2bf(b.x, b.y); o.w = pack2bf(b.z, b.w);
        wb[i] = o;
    } else {                                        // zero cur[391] + sums[12800]
        int idx = (bid - 6282) * 256 + t;           // 16 blocks -> 4096 threads
        for (int i = idx; i < N_GRAPHS * NF; i += 4096) sums[i] = 0.f;
        if (idx < NBKT) cur[idx] = 0;
    }
}

// ---------------------------------------------------------------- CSR A: scatter edges into fixed-cap coarse buckets
// packed entry: (dstLocal<<17) | src   (src < 131072, dstLocal < 256)
// R7: EPB 2048 -> 782 blocks (3.05/CU, was 1.53/CU). Pure rebalance, no extra work.
__global__ __launch_bounds__(512) void bscatter(const int* __restrict__ src,
                                                const int* __restrict__ dst,
                                                int* __restrict__ cur,
                                                uint32* __restrict__ ebuf) {
    __shared__ int lh[NBKT], lbase[NBKT];
    int t = threadIdx.x;
    if (t < NBKT) lh[t] = 0;
    __syncthreads();
    int e0 = blockIdx.x * EPB;
    int d[4];
    #pragma unroll
    for (int i = 0; i < 4; ++i) {
        int e = e0 + i * 512 + t;
        d[i] = -1;
        if (e < N_EDGES) { d[i] = dst[e]; atomicAdd(&lh[d[i] >> BKT_SHIFT], 1); }
    }
    __syncthreads();
    if (t < NBKT) { lbase[t] = t * CAP + (lh[t] ? atomicAdd(&cur[t], lh[t]) : 0); lh[t] = 0; }
    __syncthreads();
    #pragma unroll
    for (int i = 0; i < 4; ++i) {
        int e = e0 + i * 512 + t;
        if (e < N_EDGES) {
            int b = d[i] >> BKT_SHIFT;
            int off = atomicAdd(&lh[b], 1);
            ebuf[lbase[b] + off] = ((uint32)(d[i] & 255) << 17) | (uint32)src[e];
        }
    }
}

// ---------------------------------------------------------------- CSR B (R3-proven): bucket -> fixed-cap per-node rows via LDS
__global__ __launch_bounds__(256) void bfine(const uint32* __restrict__ ebuf,
                                             const int* __restrict__ cur,
                                             int* __restrict__ cnt,
                                             int* __restrict__ csr) {
    __shared__ int off[256];
    __shared__ __align__(16) int lcsr[256 * CAPN];  // 49KB
    int t = threadIdx.x;
    int bkt = blockIdx.x;
    int beg = bkt * CAP;
    int end = beg + min(cur[bkt], CAP);
    off[t] = 0;
    __syncthreads();
    for (int e = beg + t; e < end; e += 256) {
        uint32 u = ebuf[e];
        int local = (int)(u >> 17);
        int pos = atomicAdd(&off[local], 1);
        if (pos < CAPN)
            lcsr[local * CAPN + pos] = (int)(u & 0x1FFFFu);
    }
    __syncthreads();
    int node = (bkt << BKT_SHIFT) + t;
    if (node < N_NODES) cnt[node] = min(off[t], CAPN);
    uint4* dstq = (uint4*)(csr + (size_t)bkt * 256 * CAPN);
    const uint4* srcq = (const uint4*)lcsr;
    for (int i = t; i < 256 * CAPN / 4; i += 256)   // 3072 uint4, fully coalesced
        dstq[i] = srcq[i];
}

// ---------------------------------------------------------------- bf16 gather v3 (R1-exact, 59us measured): one WAVE per node
// DO NOT serialize nodes within a wave or attach LDS: the 25000-block churn IS
// the memory-level parallelism (R2/R6 lessons).
__global__ __launch_bounds__(256) void gather_agg_bf16(const uint4* __restrict__ x,
                                                       const int* __restrict__ cnt,
                                                       const int* __restrict__ csr,
                                                       uint4* __restrict__ out) {
    int gid  = blockIdx.x * 256 + threadIdx.x;
    int node = gid >> 6;
    int l = threadIdx.x & 63;
    int c = l & 15;              // feature chunk (16B)
    int j = l >> 4;              // edge slot 0..3
    int beg = node * CAPN;

    uint4 vself = x[(size_t)node * 16 + c];          // independent: issue first
    int myE = csr[beg + min(l, CAPN - 1)];           // lanes 0..47 hold the row
    int deg = cnt[node];                             // wave-uniform broadcast load

    f32x2 acc[4];
    #pragma unroll
    for (int i = 0; i < 4; ++i) acc[i] = (f32x2){0.f, 0.f};

    uint4 v[8];
    int ok[8];
    #pragma unroll
    for (int k = 0; k < 4; ++k) {                    // tile 0: slots 0..15
        int sl = j + 4 * k;
        int sle = max(min(sl, deg - 1), 0);          // deg==0 safe
        unsigned s = (unsigned)__shfl(myE, sle, 64);
        s = min(s, (unsigned)(N_NODES - 1));         // garbage-entry clamp (in-bounds)
        v[k] = x[(size_t)s * 16 + c];
        ok[k] = sl < deg;
    }
    if (deg > 16) {                                  // tile 1: slots 16..31 (uniform branch)
        #pragma unroll
        for (int k = 0; k < 4; ++k) {
            int sl = 16 + j + 4 * k;
            int sle = min(sl, deg - 1);
            unsigned s = (unsigned)__shfl(myE, sle, 64);
            s = min(s, (unsigned)(N_NODES - 1));
            v[4 + k] = x[(size_t)s * 16 + c];
            ok[4 + k] = sl < deg;
        }
    }
    #pragma unroll
    for (int k = 0; k < 4; ++k) if (ok[k]) add8(acc, v[k]);
    if (deg > 16) {
        #pragma unroll
        for (int k = 0; k < 4; ++k) if (ok[4 + k]) add8(acc, v[4 + k]);
        for (int sl0 = 32; sl0 < deg; sl0 += 16) {   // rare tail: P(deg>32) ~ 1e-4
            #pragma unroll
            for (int k = 0; k < 4; ++k) {
                int sl = sl0 + j + 4 * k;
                int sle = min(sl, deg - 1);
                unsigned s = (unsigned)__shfl(myE, sle, 64);
                s = min(s, (unsigned)(N_NODES - 1));
                uint4 vv = x[(size_t)s * 16 + c];
                if (sl < deg) add8(acc, vv);
            }
        }
    }

    // reduce the 4 edge-slot partials: lanes l, l^16, l^32, l^48 share chunk c
    #pragma unroll
    for (int i = 0; i < 4; ++i) {
        acc[i].x += __shfl_xor(acc[i].x, 16, 64);
        acc[i].y += __shfl_xor(acc[i].y, 16, 64);
        acc[i].x += __shfl_xor(acc[i].x, 32, 64);
        acc[i].y += __shfl_xor(acc[i].y, 32, 64);
    }

    add8(acc, vself);                                // self term

    if (j == 0) {
        uint4 o;
        o.x = pack2bf(acc[0].x, acc[0].y); o.y = pack2bf(acc[1].x, acc[1].y);
        o.z = pack2bf(acc[2].x, acc[2].y); o.w = pack2bf(acc[3].x, acc[3].y);
        out[(size_t)node * 16 + c] = o;              // 16 lanes x 16B contiguous
    }
}

// ---------------------------------------------------------------- R7 mlp64: fused 2-layer MLP, 64 rows/block
// C = relu(relu(A Wa^T + ba) Wb^T + bb). 256 thr = 4 waves x 16 rows. Mid LDS
// 64x136 = 17.4KB -> 8 blocks/CU; launch_bounds(256,8) caps VGPR at 64 ->
// target ~32 waves/CU (old 128-row version: 35KB LDS, 4 blocks/CU, 50%).
// POOL: mlp2 also accumulates graph-mean sums (batch sorted; a 16-row tile is
// single-graph except at ~100 graph boundaries since min graph size ~900).
template <bool F32OUT, bool POOL>
__global__ __launch_bounds__(256, 8) void mlp64(const unsigned short* __restrict__ A,
                                                const unsigned short* __restrict__ Wa,
                                                const float* __restrict__ ba,
                                                const unsigned short* __restrict__ Wb,
                                                const float* __restrict__ bb,
                                                void* __restrict__ Cout,
                                                const int* __restrict__ batch,
                                                float* __restrict__ sums) {
    __shared__ __align__(16) unsigned short Mid[64 * 136];
    int tid = threadIdx.x;
    int wv = tid >> 6, l = tid & 63, lm = l & 15, q = l >> 4;
    int row0  = blockIdx.x * 64;
    int trow0 = row0 + wv * 16;                      // wave's 16-row tile

    const unsigned short* pa  = A + (size_t)min(trow0 + lm, N_NODES - 1) * NF;
    const unsigned short* pwa = Wa + lm * NF;
    const unsigned short* pwb = Wb + lm * NF;

    f32x4 acc[8];
    #pragma unroll
    for (int ct = 0; ct < 8; ++ct) acc[ct] = (f32x4){0.f, 0.f, 0.f, 0.f};

    #pragma unroll
    for (int ks = 0; ks < 4; ++ks) {                 // pass 1: mid = A @ Wa^T
        int ko = ks * 32 + q * 8;
        bf16x8 a = *(const bf16x8*)(pa + ko);
        #pragma unroll
        for (int ct = 0; ct < 8; ++ct) {
            bf16x8 b = *(const bf16x8*)(pwa + ct * 16 * NF + ko);
            acc[ct] = __builtin_amdgcn_mfma_f32_16x16x32_bf16(a, b, acc[ct], 0, 0, 0);
        }
    }

    #pragma unroll
    for (int ct = 0; ct < 8; ++ct) {                 // mid -> LDS (bias+relu+bf16)
        int col = ct * 16 + lm;
        float bv = ba[col];
        #pragma unroll
        for (int r = 0; r < 4; ++r) {
            int rr = wv * 16 + q * 4 + r;
            Mid[rr * 136 + col] = f2bf(fmaxf(acc[ct][r] + bv, 0.f));
        }
    }
    __syncthreads();

    #pragma unroll
    for (int ct = 0; ct < 8; ++ct) acc[ct] = (f32x4){0.f, 0.f, 0.f, 0.f};

    const unsigned short* pm = &Mid[(wv * 16 + lm) * 136];
    #pragma unroll
    for (int ks = 0; ks < 4; ++ks) {                 // pass 2: out = mid @ Wb^T
        int ko = ks * 32 + q * 8;
        bf16x8 a = *(const bf16x8*)(pm + ko);
        #pragma unroll
        for (int ct = 0; ct < 8; ++ct) {
            bf16x8 b = *(const bf16x8*)(pwb + ct * 16 * NF + ko);
            acc[ct] = __builtin_amdgcn_mfma_f32_16x16x32_bf16(a, b, acc[ct], 0, 0, 0);
        }
    }

    // ---- epilogue (+ optional fused graph-sum pooling)
    int gr[4];
    bool uni = true;
    if (POOL) {
        int gA = batch[min(trow0,      N_NODES - 1)];
        int gB = batch[min(trow0 + 15, N_NODES - 1)];
        uni = (gA == gB);
        gr[0] = gA;
        if (!uni) {
            #pragma unroll
            for (int r = 0; r < 4; ++r)
                gr[r] = batch[min(trow0 + q * 4 + r, N_NODES - 1)];
        }
    }

    #pragma unroll
    for (int ct = 0; ct < 8; ++ct) {
        int col = ct * 16 + lm;
        float bv = bb[col];
        float ps = 0.f;
        #pragma unroll
        for (int r = 0; r < 4; ++r) {
            int row = trow0 + q * 4 + r;
            if (row < N_NODES) {
                float vv = fmaxf(acc[ct][r] + bv, 0.f);
                if (F32OUT) ((float*)Cout)[(size_t)row * NF + col] = vv;
                else ((unsigned short*)Cout)[(size_t)row * NF + col] = f2bf(vv);
                if (POOL) {
                    if (uni) ps += vv;
                    else atomicAdd(&sums[gr[r] * NF + col], vv);   // boundary tiles only
                }
            }
        }
        if (POOL && uni) {                           // reduce 4 q-slots -> 1 atomic
            ps += __shfl_xor(ps, 16, 64);
            ps += __shfl_xor(ps, 32, 64);
            if (q == 0) atomicAdd(&sums[gr[0] * NF + col], ps);
        }
    }
}

// ---------------------------------------------------------------- pool divide (sums already accumulated by mlp2)
__global__ __launch_bounds__(256) void pool_div2(const float* __restrict__ sums,
                                                 const int* __restrict__ batch,
                                                 float* __restrict__ out) {
    int i = blockIdx.x * 256 + threadIdx.x;
    if (i >= N_GRAPHS * NF) return;
    int g = i >> 7;
    int lo = 0, hi = N_NODES;
    while (lo < hi) { int m = (lo + hi) >> 1; if (batch[m] < g) lo = m + 1; else hi = m; }
    int lo2 = lo, hi2 = N_NODES;
    while (lo2 < hi2) { int m = (lo2 + hi2) >> 1; if (batch[m] < g + 1) lo2 = m + 1; else hi2 = m; }
    float cnt = (float)(lo2 - lo);
    out[i] = sums[i] / fmaxf(cnt, 1.f);
}

// ----------------------------------------------------------------
extern "C" void kernel_launch(void* const* d_in, const int* in_sizes, int n_in,
                              void* d_out, int out_size, void* d_ws, size_t ws_size,
                              hipStream_t stream) {
    const float* x     = (const float*)d_in[0];
    const int*   ei    = (const int*)d_in[1];
    const int*   batch = (const int*)d_in[2];
    const float* W1 = (const float*)d_in[3];  const float* b1 = (const float*)d_in[4];
    const float* W2 = (const float*)d_in[5];  const float* b2 = (const float*)d_in[6];
    const float* W3 = (const float*)d_in[7];  const float* b3 = (const float*)d_in[8];
    const float* W4 = (const float*)d_in[9];  const float* b4 = (const float*)d_in[10];
    const int* src = ei;
    const int* dst = ei + N_EDGES;

    float* out   = (float*)d_out;
    float* h_out = out + N_GRAPHS * NF;            // 100000x128 fp32 (2nd output)

    // workspace (~96.7 MB; ebuf aliases t1 — t1 first written by mlp1, after bfine)
    const size_t NE = (size_t)N_NODES * NF;        // 12.8M
    unsigned short* xb = (unsigned short*)d_ws;    // bf16 x            25.6 MB
    unsigned short* t0 = xb + NE;                  //                   25.6 MB
    unsigned short* t1 = t0 + NE;                  //                   25.6 MB
    unsigned short* Wb = t1 + NE;                  // 4 x 128x128 bf16  0.13 MB
    int*    csr  = (int*)(Wb + 4 * NF * NF);       // NBKT*256*CAPN     19.2 MB (bucket-padded)
    int*    cntp = csr + (size_t)NBKT * 256 * CAPN;// N_NODES           0.4 MB
    int*    curp = cntp + N_NODES;                 // NBKT
    float*  sums = (float*)(curp + NBKT);          // N_GRAPHS*NF
    uint32* ebuf = (uint32*)t1;                    // alias: 9.6 MB <= 25.6 MB

    const int gather_blocks = N_NODES * 64 / 256;  // 25000 (one wave per node)

    // ---- prep: bf16 conversions + zero cursors/sums (one launch, no memsets)
    prep<<<6250 + 32 + 16, 256, 0, stream>>>((const float4*)x,
                                             (const float4*)W1, (const float4*)W2,
                                             (const float4*)W3, (const float4*)W4,
                                             (uint4*)xb, (uint4*)Wb, curp, sums);

    // ---- CSR build (coarse bucket scatter, then LDS-staged fixed-cap rows)
    bscatter<<<EB_GRID, 512, 0, stream>>>(src, dst, curp, ebuf);
    bfine<<<NBKT, 256, 0, stream>>>(ebuf, curp, cntp, csr);

    // ---- layer group 1: agg + fused MLP1
    gather_agg_bf16<<<gather_blocks, 256, 0, stream>>>((const uint4*)xb, cntp, csr, (uint4*)t0);
    mlp64<false, false><<<MBLK64, 256, 0, stream>>>(t0, Wb + 0 * NF * NF, b1,
                                                    Wb + 1 * NF * NF, b2, t1, batch, sums);

    // ---- layer group 2: agg + fused MLP2 (+ fused pool accumulation)
    gather_agg_bf16<<<gather_blocks, 256, 0, stream>>>((const uint4*)t1, cntp, csr, (uint4*)t0);
    mlp64<true, true><<<MBLK64, 256, 0, stream>>>(t0, Wb + 2 * NF * NF, b3,
                                                  Wb + 3 * NF * NF, b4, h_out, batch, sums);

    // ---- global mean pool (divide only)
    pool_div2<<<(N_GRAPHS * NF + 255) / 256, 256, 0, stream>>>(sums, batch, out);
}

// Round 8
// 388.021 us; speedup vs baseline: 1.2043x; 1.1324x over previous
//
#include <hip/hip_runtime.h>

#define N_NODES  100000
#define N_EDGES  1600000
#define NF       128
#define N_GRAPHS 100
#define NBKT     391         // ceil(100000 / 256) coarse buckets
#define BKT_SHIFT 8
#define CAP      6144        // coarse bucket capacity; mean 4092, +32 sigma (fixed input)
#define CAPN     48          // per-node CSR capacity; Poisson(16), P(deg>48) ~ 7e-11/node
#define EPB      2048        // edges per block in bscatter (782 blocks = 3.05/CU)
#define EB_GRID  782
#define MBLK     782         // ceil(100000/128) mlp blocks

typedef __attribute__((ext_vector_type(8))) short bf16x8;
typedef __attribute__((ext_vector_type(4))) float f32x4;
typedef __attribute__((ext_vector_type(2))) float f32x2;
typedef unsigned int uint32;

// ---------------------------------------------------------------- bf16 helpers (RNE)
__device__ __forceinline__ unsigned short f2bf(float f) {
    union { float f; uint32 u; } x; x.f = f;
    return (unsigned short)((x.u + 0x7fffu + ((x.u >> 16) & 1u)) >> 16);
}
__device__ __forceinline__ uint32 pack2bf(float a, float b) {
    union { float f; uint32 u; } x, y; x.f = a; y.f = b;
    uint32 lo = (x.u + 0x7fffu + ((x.u >> 16) & 1u)) >> 16;
    uint32 hi = (y.u + 0x7fffu + ((y.u >> 16) & 1u)) & 0xffff0000u;
    return lo | hi;
}
__device__ __forceinline__ void add8(f32x2* acc, uint4 u4) {
    uint32 u[4] = {u4.x, u4.y, u4.z, u4.w};
    #pragma unroll
    for (int i = 0; i < 4; ++i) {
        union { uint32 b; float f; } lo, hi;
        lo.b = u[i] << 16; hi.b = u[i] & 0xffff0000u;
        acc[i] += (f32x2){lo.f, hi.f};
    }
}

// ---------------------------------------------------------------- prep (R1-proven): x->bf16, W1..4->bf16, zero cursors+sums
__global__ __launch_bounds__(256) void prep(const float4* __restrict__ x,
                                            const float4* __restrict__ w1,
                                            const float4* __restrict__ w2,
                                            const float4* __restrict__ w3,
                                            const float4* __restrict__ w4,
                                            uint4* __restrict__ xb, uint4* __restrict__ wb,
                                            int* __restrict__ cur, float* __restrict__ sums) {
    int bid = blockIdx.x, t = threadIdx.x;
    if (bid < 6250) {                               // x: 1.6M uint4 outputs exactly
        int i = bid * 256 + t;
        float4 a = x[i * 2], b = x[i * 2 + 1];
        uint4 o;
        o.x = pack2bf(a.x, a.y); o.y = pack2bf(a.z, a.w);
        o.z = pack2bf(b.x, b.y); o.w = pack2bf(b.z, b.w);
        xb[i] = o;
    } else if (bid < 6282) {                        // weights: 8192 uint4
        int i = (bid - 6250) * 256 + t;
        int wi = i >> 11, li = i & 2047;
        const float4* s = (wi == 0) ? w1 : (wi == 1) ? w2 : (wi == 2) ? w3 : w4;
        float4 a = s[li * 2], b = s[li * 2 + 1];
        uint4 o;
        o.x = pack2bf(a.x, a.y); o.y = pack2bf(a.z, a.w);
        o.z = pack2bf(b.x, b.y); o.w = pack2bf(b.z, b.w);
        wb[i] = o;
    } else {                                        // zero cur[391] + sums[12800]
        int idx = (bid - 6282) * 256 + t;           // 16 blocks -> 4096 threads
        for (int i = idx; i < N_GRAPHS * NF; i += 4096) sums[i] = 0.f;
        if (idx < NBKT) cur[idx] = 0;
    }
}

// ---------------------------------------------------------------- CSR A: scatter edges into fixed-cap coarse buckets
// packed entry: (dstLocal<<17) | src   (src < 131072, dstLocal < 256)
__global__ __launch_bounds__(512) void bscatter(const int* __restrict__ src,
                                                const int* __restrict__ dst,
                                                int* __restrict__ cur,
                                                uint32* __restrict__ ebuf) {
    __shared__ int lh[NBKT], lbase[NBKT];
    int t = threadIdx.x;
    if (t < NBKT) lh[t] = 0;
    __syncthreads();
    int e0 = blockIdx.x * EPB;
    int d[4];
    #pragma unroll
    for (int i = 0; i < 4; ++i) {
        int e = e0 + i * 512 + t;
        d[i] = -1;
        if (e < N_EDGES) { d[i] = dst[e]; atomicAdd(&lh[d[i] >> BKT_SHIFT], 1); }
    }
    __syncthreads();
    if (t < NBKT) { lbase[t] = t * CAP + (lh[t] ? atomicAdd(&cur[t], lh[t]) : 0); lh[t] = 0; }
    __syncthreads();
    #pragma unroll
    for (int i = 0; i < 4; ++i) {
        int e = e0 + i * 512 + t;
        if (e < N_EDGES) {
            int b = d[i] >> BKT_SHIFT;
            int off = atomicAdd(&lh[b], 1);
            ebuf[lbase[b] + off] = ((uint32)(d[i] & 255) << 17) | (uint32)src[e];
        }
    }
}

// ---------------------------------------------------------------- CSR B (R3-proven): bucket -> fixed-cap per-node rows via LDS
__global__ __launch_bounds__(256) void bfine(const uint32* __restrict__ ebuf,
                                             const int* __restrict__ cur,
                                             int* __restrict__ cnt,
                                             int* __restrict__ csr) {
    __shared__ int off[256];
    __shared__ __align__(16) int lcsr[256 * CAPN];  // 49KB
    int t = threadIdx.x;
    int bkt = blockIdx.x;
    int beg = bkt * CAP;
    int end = beg + min(cur[bkt], CAP);
    off[t] = 0;
    __syncthreads();
    for (int e = beg + t; e < end; e += 256) {
        uint32 u = ebuf[e];
        int local = (int)(u >> 17);
        int pos = atomicAdd(&off[local], 1);
        if (pos < CAPN)
            lcsr[local * CAPN + pos] = (int)(u & 0x1FFFFu);
    }
    __syncthreads();
    int node = (bkt << BKT_SHIFT) + t;
    if (node < N_NODES) cnt[node] = min(off[t], CAPN);
    uint4* dstq = (uint4*)(csr + (size_t)bkt * 256 * CAPN);
    const uint4* srcq = (const uint4*)lcsr;
    for (int i = t; i < 256 * CAPN / 4; i += 256)   // 3072 uint4, fully coalesced
        dstq[i] = srcq[i];
}

// ---------------------------------------------------------------- bf16 gather v3 (R1-exact, 59us measured): one WAVE per node
// DO NOT serialize nodes within a wave or attach LDS: the 25000-block churn IS
// the memory-level parallelism (R2/R6 lessons).
__global__ __launch_bounds__(256) void gather_agg_bf16(const uint4* __restrict__ x,
                                                       const int* __restrict__ cnt,
                                                       const int* __restrict__ csr,
                                                       uint4* __restrict__ out) {
    int gid  = blockIdx.x * 256 + threadIdx.x;
    int node = gid >> 6;
    int l = threadIdx.x & 63;
    int c = l & 15;              // feature chunk (16B)
    int j = l >> 4;              // edge slot 0..3
    int beg = node * CAPN;

    uint4 vself = x[(size_t)node * 16 + c];          // independent: issue first
    int myE = csr[beg + min(l, CAPN - 1)];           // lanes 0..47 hold the row
    int deg = cnt[node];                             // wave-uniform broadcast load

    f32x2 acc[4];
    #pragma unroll
    for (int i = 0; i < 4; ++i) acc[i] = (f32x2){0.f, 0.f};

    uint4 v[8];
    int ok[8];
    #pragma unroll
    for (int k = 0; k < 4; ++k) {                    // tile 0: slots 0..15
        int sl = j + 4 * k;
        int sle = max(min(sl, deg - 1), 0);          // deg==0 safe
        unsigned s = (unsigned)__shfl(myE, sle, 64);
        s = min(s, (unsigned)(N_NODES - 1));         // garbage-entry clamp (in-bounds)
        v[k] = x[(size_t)s * 16 + c];
        ok[k] = sl < deg;
    }
    if (deg > 16) {                                  // tile 1: slots 16..31 (uniform branch)
        #pragma unroll
        for (int k = 0; k < 4; ++k) {
            int sl = 16 + j + 4 * k;
            int sle = min(sl, deg - 1);
            unsigned s = (unsigned)__shfl(myE, sle, 64);
            s = min(s, (unsigned)(N_NODES - 1));
            v[4 + k] = x[(size_t)s * 16 + c];
            ok[4 + k] = sl < deg;
        }
    }
    #pragma unroll
    for (int k = 0; k < 4; ++k) if (ok[k]) add8(acc, v[k]);
    if (deg > 16) {
        #pragma unroll
        for (int k = 0; k < 4; ++k) if (ok[4 + k]) add8(acc, v[4 + k]);
        for (int sl0 = 32; sl0 < deg; sl0 += 16) {   // rare tail: P(deg>32) ~ 1e-4
            #pragma unroll
            for (int k = 0; k < 4; ++k) {
                int sl = sl0 + j + 4 * k;
                int sle = min(sl, deg - 1);
                unsigned s = (unsigned)__shfl(myE, sle, 64);
                s = min(s, (unsigned)(N_NODES - 1));
                uint4 vv = x[(size_t)s * 16 + c];
                if (sl < deg) add8(acc, vv);
            }
        }
    }

    // reduce the 4 edge-slot partials: lanes l, l^16, l^32, l^48 share chunk c
    #pragma unroll
    for (int i = 0; i < 4; ++i) {
        acc[i].x += __shfl_xor(acc[i].x, 16, 64);
        acc[i].y += __shfl_xor(acc[i].y, 16, 64);
        acc[i].x += __shfl_xor(acc[i].x, 32, 64);
        acc[i].y += __shfl_xor(acc[i].y, 32, 64);
    }

    add8(acc, vself);                                // self term

    if (j == 0) {
        uint4 o;
        o.x = pack2bf(acc[0].x, acc[0].y); o.y = pack2bf(acc[1].x, acc[1].y);
        o.z = pack2bf(acc[2].x, acc[2].y); o.w = pack2bf(acc[3].x, acc[3].y);
        out[(size_t)node * 16 + c] = o;              // 16 lanes x 16B contiguous
    }
}

// ---------------------------------------------------------------- R8 mlp: 128 rows/block, LDS-staged COALESCED writes
// C = relu(relu(A Wa^T + ba) Wb^T + bb). R7 post-mortem: the scalar epilogue's
// 32-64B partial-line stores amplified WRITE_SIZE 2-4x (95.8MB vs 25.6 logical)
// and made the MLP write-bound at 86us. Fix: stage the output tile in LDS, then
// write full 256B (bf16) / 512B (f32) rows as uint4/float4. POOL: mlp2 also
// accumulates graph-mean sums from registers (batch sorted, R7-proven).
template <bool F32OUT, bool POOL>
__global__ __launch_bounds__(256, 4) void mlp_mfma(const unsigned short* __restrict__ A,
                                                   const unsigned short* __restrict__ Wa,
                                                   const float* __restrict__ ba,
                                                   const unsigned short* __restrict__ Wb,
                                                   const float* __restrict__ bb,
                                                   void* __restrict__ Cout,
                                                   const int* __restrict__ batch,
                                                   float* __restrict__ sums) {
    __shared__ __align__(16) unsigned short Mid[128 * 136];  // 34.8KB; reused for out-staging
    int tid  = threadIdx.x;
    int row0 = blockIdx.x * 128;
    int wv = tid >> 6, l = tid & 63, lm = l & 15, q = l >> 4;

    const unsigned short* pa0 = A + (size_t)min(row0 + wv * 32 + lm,      N_NODES - 1) * NF;
    const unsigned short* pa1 = A + (size_t)min(row0 + wv * 32 + 16 + lm, N_NODES - 1) * NF;
    const unsigned short* pwa = Wa + lm * NF;
    const unsigned short* pwb = Wb + lm * NF;

    f32x4 acc[2][8];
    #pragma unroll
    for (int i = 0; i < 2; ++i)
        #pragma unroll
        for (int j = 0; j < 8; ++j) acc[i][j] = (f32x4){0.f, 0.f, 0.f, 0.f};

    #pragma unroll
    for (int ks = 0; ks < 4; ++ks) {                // pass 1: mid = A @ Wa^T
        int ko = ks * 32 + q * 8;
        bf16x8 a0 = *(const bf16x8*)(pa0 + ko);
        bf16x8 a1 = *(const bf16x8*)(pa1 + ko);
        #pragma unroll
        for (int ct = 0; ct < 8; ++ct) {
            bf16x8 b = *(const bf16x8*)(pwa + ct * 16 * NF + ko);
            acc[0][ct] = __builtin_amdgcn_mfma_f32_16x16x32_bf16(a0, b, acc[0][ct], 0, 0, 0);
            acc[1][ct] = __builtin_amdgcn_mfma_f32_16x16x32_bf16(a1, b, acc[1][ct], 0, 0, 0);
        }
    }

    #pragma unroll
    for (int rt = 0; rt < 2; ++rt)                  // mid -> LDS (bias+relu+bf16)
        #pragma unroll
        for (int ct = 0; ct < 8; ++ct) {
            int col = ct * 16 + lm;
            float bv = ba[col];
            #pragma unroll
            for (int r = 0; r < 4; ++r) {
                int rr = wv * 32 + rt * 16 + q * 4 + r;
                Mid[rr * 136 + col] = f2bf(fmaxf(acc[rt][ct][r] + bv, 0.f));
            }
        }
    __syncthreads();

    #pragma unroll
    for (int i = 0; i < 2; ++i)
        #pragma unroll
        for (int j = 0; j < 8; ++j) acc[i][j] = (f32x4){0.f, 0.f, 0.f, 0.f};

    const unsigned short* pm0 = &Mid[(wv * 32 + lm) * 136];
    const unsigned short* pm1 = &Mid[(wv * 32 + 16 + lm) * 136];
    #pragma unroll
    for (int ks = 0; ks < 4; ++ks) {                // pass 2: out = mid @ Wb^T
        int ko = ks * 32 + q * 8;
        bf16x8 a0 = *(const bf16x8*)(pm0 + ko);
        bf16x8 a1 = *(const bf16x8*)(pm1 + ko);
        #pragma unroll
        for (int ct = 0; ct < 8; ++ct) {
            bf16x8 b = *(const bf16x8*)(pwb + ct * 16 * NF + ko);
            acc[0][ct] = __builtin_amdgcn_mfma_f32_16x16x32_bf16(a0, b, acc[0][ct], 0, 0, 0);
            acc[1][ct] = __builtin_amdgcn_mfma_f32_16x16x32_bf16(a1, b, acc[1][ct], 0, 0, 0);
        }
    }
    __syncthreads();                                // all pass-2 LDS reads done before re-staging

    // ---- fused graph-sum pooling (from registers; batch sorted; uni-tile fast path)
    if (POOL) {
        #pragma unroll
        for (int rt = 0; rt < 2; ++rt) {
            int trow0 = row0 + wv * 32 + rt * 16;
            int gA = batch[min(trow0,      N_NODES - 1)];
            int gB = batch[min(trow0 + 15, N_NODES - 1)];
            bool uni = (gA == gB);
            #pragma unroll
            for (int ct = 0; ct < 8; ++ct) {
                int col = ct * 16 + lm;
                float bv = bb[col];
                float ps = 0.f;
                #pragma unroll
                for (int r = 0; r < 4; ++r) {
                    int row = trow0 + q * 4 + r;
                    if (row < N_NODES) {
                        float vv = fmaxf(acc[rt][ct][r] + bv, 0.f);
                        if (uni) ps += vv;
                        else atomicAdd(&sums[batch[row] * NF + col], vv);  // boundary tiles only
                    }
                }
                if (uni) {                          // reduce 4 q-slots -> 1 atomic
                    ps += __shfl_xor(ps, 16, 64);
                    ps += __shfl_xor(ps, 32, 64);
                    if (q == 0) atomicAdd(&sums[gA * NF + col], ps);
                }
            }
        }
    }

    // ---- epilogue: stage in LDS, write FULL LINES
    if (!F32OUT) {
        #pragma unroll
        for (int rt = 0; rt < 2; ++rt)              // re-stage bf16 out into Mid
            #pragma unroll
            for (int ct = 0; ct < 8; ++ct) {
                int col = ct * 16 + lm;
                float bv = bb[col];
                #pragma unroll
                for (int r = 0; r < 4; ++r) {
                    int rr = wv * 32 + rt * 16 + q * 4 + r;
                    Mid[rr * 136 + col] = f2bf(fmaxf(acc[rt][ct][r] + bv, 0.f));
                }
            }
        __syncthreads();
        for (int i = tid; i < 128 * 16; i += 256) { // 128 rows x 256B, fully coalesced
            int row = i >> 4, c = i & 15;
            if (row0 + row < N_NODES)
                ((uint4*)Cout)[(size_t)(row0 + row) * 16 + c] = *(const uint4*)&Mid[row * 136 + c * 8];
        }
    } else {
        float* Mf = (float*)Mid;                    // stride 132 f32: 64*132*4 = 33.8KB <= 34.8KB
        #pragma unroll
        for (int h = 0; h < 2; ++h) {               // two 64-row halves
            if ((wv >> 1) == h) {                   // waves owning rows [h*64, h*64+64)
                #pragma unroll
                for (int rt = 0; rt < 2; ++rt)
                    #pragma unroll
                    for (int ct = 0; ct < 8; ++ct) {
                        int col = ct * 16 + lm;
                        float bv = bb[col];
                        #pragma unroll
                        for (int r = 0; r < 4; ++r) {
                            int lr = (wv & 1) * 32 + rt * 16 + q * 4 + r;
                            Mf[lr * 132 + col] = fmaxf(acc[rt][ct][r] + bv, 0.f);
                        }
                    }
            }
            __syncthreads();
            for (int i = tid; i < 64 * 32; i += 256) {  // 64 rows x 512B, fully coalesced
                int lr = i >> 5, c = i & 31;
                int row = row0 + h * 64 + lr;
                if (row < N_NODES)
                    ((float4*)Cout)[(size_t)row * 32 + c] = *(const float4*)&Mf[lr * 132 + c * 4];
            }
            __syncthreads();
        }
    }
}

// ---------------------------------------------------------------- pool divide (sums already accumulated by mlp2)
__global__ __launch_bounds__(256) void pool_div2(const float* __restrict__ sums,
                                                 const int* __restrict__ batch,
                                                 float* __restrict__ out) {
    int i = blockIdx.x * 256 + threadIdx.x;
    if (i >= N_GRAPHS * NF) return;
    int g = i >> 7;
    int lo = 0, hi = N_NODES;
    while (lo < hi) { int m = (lo + hi) >> 1; if (batch[m] < g) lo = m + 1; else hi = m; }
    int lo2 = lo, hi2 = N_NODES;
    while (lo2 < hi2) { int m = (lo2 + hi2) >> 1; if (batch[m] < g + 1) lo2 = m + 1; else hi2 = m; }
    float cnt = (float)(lo2 - lo);
    out[i] = sums[i] / fmaxf(cnt, 1.f);
}

// ----------------------------------------------------------------
extern "C" void kernel_launch(void* const* d_in, const int* in_sizes, int n_in,
                              void* d_out, int out_size, void* d_ws, size_t ws_size,
                              hipStream_t stream) {
    const float* x     = (const float*)d_in[0];
    const int*   ei    = (const int*)d_in[1];
    const int*   batch = (const int*)d_in[2];
    const float* W1 = (const float*)d_in[3];  const float* b1 = (const float*)d_in[4];
    const float* W2 = (const float*)d_in[5];  const float* b2 = (const float*)d_in[6];
    const float* W3 = (const float*)d_in[7];  const float* b3 = (const float*)d_in[8];
    const float* W4 = (const float*)d_in[9];  const float* b4 = (const float*)d_in[10];
    const int* src = ei;
    const int* dst = ei + N_EDGES;

    float* out   = (float*)d_out;
    float* h_out = out + N_GRAPHS * NF;            // 100000x128 fp32 (2nd output)

    // workspace (~96.7 MB; ebuf aliases t1 — t1 first written by mlp1, after bfine)
    const size_t NE = (size_t)N_NODES * NF;        // 12.8M
    unsigned short* xb = (unsigned short*)d_ws;    // bf16 x            25.6 MB
    unsigned short* t0 = xb + NE;                  //                   25.6 MB
    unsigned short* t1 = t0 + NE;                  //                   25.6 MB
    unsigned short* Wb = t1 + NE;                  // 4 x 128x128 bf16  0.13 MB
    int*    csr  = (int*)(Wb + 4 * NF * NF);       // NBKT*256*CAPN     19.2 MB (bucket-padded)
    int*    cntp = csr + (size_t)NBKT * 256 * CAPN;// N_NODES           0.4 MB
    int*    curp = cntp + N_NODES;                 // NBKT
    float*  sums = (float*)(curp + NBKT);          // N_GRAPHS*NF
    uint32* ebuf = (uint32*)t1;                    // alias: 9.6 MB <= 25.6 MB

    const int gather_blocks = N_NODES * 64 / 256;  // 25000 (one wave per node)

    // ---- prep: bf16 conversions + zero cursors/sums (one launch, no memsets)
    prep<<<6250 + 32 + 16, 256, 0, stream>>>((const float4*)x,
                                             (const float4*)W1, (const float4*)W2,
                                             (const float4*)W3, (const float4*)W4,
                                             (uint4*)xb, (uint4*)Wb, curp, sums);

    // ---- CSR build (coarse bucket scatter, then LDS-staged fixed-cap rows)
    bscatter<<<EB_GRID, 512, 0, stream>>>(src, dst, curp, ebuf);
    bfine<<<NBKT, 256, 0, stream>>>(ebuf, curp, cntp, csr);

    // ---- layer group 1: agg + fused MLP1
    gather_agg_bf16<<<gather_blocks, 256, 0, stream>>>((const uint4*)xb, cntp, csr, (uint4*)t0);
    mlp_mfma<false, false><<<MBLK, 256, 0, stream>>>(t0, Wb + 0 * NF * NF, b1,
                                                     Wb + 1 * NF * NF, b2, t1, batch, sums);

    // ---- layer group 2: agg + fused MLP2 (+ fused pool accumulation)
    gather_agg_bf16<<<gather_blocks, 256, 0, stream>>>((const uint4*)t1, cntp, csr, (uint4*)t0);
    mlp_mfma<true, true><<<MBLK, 256, 0, stream>>>(t0, Wb + 2 * NF * NF, b3,
                                                   Wb + 3 * NF * NF, b4, h_out, batch, sums);

    // ---- global mean pool (divide only)
    pool_div2<<<(N_GRAPHS * NF + 255) / 256, 256, 0, stream>>>(sums, batch, out);
}